// Round 3
// baseline (79.976 us; speedup 1.0000x reference)
//
#include <hip/hip_runtime.h>
#include <math.h>

#define NN   8192
#define KF   512
#define DF   64
#define NCH  32
#define NCOL 130

// ============ K1: fused  h1 = x@W^T, s1 = h1@w1  (blocks 0..255)
// ============            s2 = n@(W^T w2)         (blocks 256..511)
__global__ __launch_bounds__(256) void k_main(const float* __restrict__ x,
        const float* __restrict__ nmat, const float* __restrict__ W,
        const float* __restrict__ w1, const float* __restrict__ w2,
        float* __restrict__ h1, float* __restrict__ s1, float* __restrict__ s2) {
    const int tid = threadIdx.x;
    if (blockIdx.x < 256) {
        // ---- GEMM path: 32 rows/block, BK=32, 2x4 micro-tile, prefetched staging
        __shared__ float xs[32][34];   // [k][row], padded for b64 alignment + banks
        __shared__ float wt[32][64];   // [k][d]
        const int row0 = blockIdx.x * 32;
        const int ty = tid >> 4, tx = tid & 15;
        const int sr = tid >> 3;           // x stage: row 0..31
        const int sc = (tid & 7) * 4;      // x stage: k-offset
        const int wd = tid & 63;           // W stage: d row
        const int wg = tid >> 6;           // W stage: k-group 0..3 (8 k's each)
        float4 xv  = *reinterpret_cast<const float4*>(x + (size_t)(row0 + sr) * KF + sc);
        float4 wv0 = *reinterpret_cast<const float4*>(W + (size_t)wd * KF + wg * 8);
        float4 wv1 = *reinterpret_cast<const float4*>(W + (size_t)wd * KF + wg * 8 + 4);
        float a00=0,a01=0,a02=0,a03=0,a10=0,a11=0,a12=0,a13=0;
        for (int kc = 0; kc < 16; ++kc) {
            __syncthreads();
            xs[sc+0][sr]=xv.x; xs[sc+1][sr]=xv.y; xs[sc+2][sr]=xv.z; xs[sc+3][sr]=xv.w;
            wt[wg*8+0][wd]=wv0.x; wt[wg*8+1][wd]=wv0.y; wt[wg*8+2][wd]=wv0.z; wt[wg*8+3][wd]=wv0.w;
            wt[wg*8+4][wd]=wv1.x; wt[wg*8+5][wd]=wv1.y; wt[wg*8+6][wd]=wv1.z; wt[wg*8+7][wd]=wv1.w;
            __syncthreads();
            if (kc < 15) {
                const int kk = (kc + 1) * 32;
                xv  = *reinterpret_cast<const float4*>(x + (size_t)(row0 + sr) * KF + kk + sc);
                wv0 = *reinterpret_cast<const float4*>(W + (size_t)wd * KF + kk + wg * 8);
                wv1 = *reinterpret_cast<const float4*>(W + (size_t)wd * KF + kk + wg * 8 + 4);
            }
            #pragma unroll
            for (int k = 0; k < 32; ++k) {
                const float2 a = *reinterpret_cast<const float2*>(&xs[k][ty * 2]);
                const float4 b = *reinterpret_cast<const float4*>(&wt[k][tx * 4]);
                a00 = fmaf(a.x, b.x, a00); a01 = fmaf(a.x, b.y, a01);
                a02 = fmaf(a.x, b.z, a02); a03 = fmaf(a.x, b.w, a03);
                a10 = fmaf(a.y, b.x, a10); a11 = fmaf(a.y, b.y, a11);
                a12 = fmaf(a.y, b.z, a12); a13 = fmaf(a.y, b.w, a13);
            }
        }
        const int r0 = row0 + ty * 2;
        *reinterpret_cast<float4*>(h1 + (size_t)r0 * DF + tx * 4)       = make_float4(a00, a01, a02, a03);
        *reinterpret_cast<float4*>(h1 + (size_t)(r0 + 1) * DF + tx * 4) = make_float4(a10, a11, a12, a13);
        const float4 wv = *reinterpret_cast<const float4*>(w1 + tx * 4);
        float p0 = a00 * wv.x + a01 * wv.y + a02 * wv.z + a03 * wv.w;
        float p1 = a10 * wv.x + a11 * wv.y + a12 * wv.z + a13 * wv.w;
        #pragma unroll
        for (int off = 1; off < 16; off <<= 1) { p0 += __shfl_xor(p0, off); p1 += __shfl_xor(p1, off); }
        if (tx == 0) { s1[r0] = p0; s1[r0 + 1] = p1; }
    } else {
        // ---- s2 path: compute v2 = W^T w2 in LDS, then 32 row-dots
        __shared__ float v2s[KF];
        const int row0 = (blockIdx.x - 256) * 32;
        float a0 = 0.f, a1 = 0.f;
        for (int d = 0; d < DF; ++d) {
            const float wd2 = w2[d];
            a0 = fmaf(W[(size_t)d * KF + tid],       wd2, a0);
            a1 = fmaf(W[(size_t)d * KF + 256 + tid], wd2, a1);
        }
        v2s[tid] = a0; v2s[tid + 256] = a1;
        __syncthreads();
        const int lane = tid & 63, w = tid >> 6;
        const float4 b0 = *reinterpret_cast<const float4*>(&v2s[lane * 4]);
        const float4 b1 = *reinterpret_cast<const float4*>(&v2s[256 + lane * 4]);
        for (int rr = 0; rr < 8; ++rr) {
            const int row = row0 + w * 8 + rr;
            const float4 n0 = *reinterpret_cast<const float4*>(nmat + (size_t)row * KF + lane * 4);
            const float4 n1 = *reinterpret_cast<const float4*>(nmat + (size_t)row * KF + 256 + lane * 4);
            float acc = n0.x * b0.x;
            acc = fmaf(n0.y, b0.y, acc); acc = fmaf(n0.z, b0.z, acc); acc = fmaf(n0.w, b0.w, acc);
            acc = fmaf(n1.x, b1.x, acc); acc = fmaf(n1.y, b1.y, acc);
            acc = fmaf(n1.z, b1.z, acc); acc = fmaf(n1.w, b1.w, acc);
            #pragma unroll
            for (int off = 32; off; off >>= 1) acc += __shfl_xor(acc, off);
            if (lane == 0) s2[row] = acc;
        }
    }
}

// ============ K2: rank all j by (s2[j], j), scatter sorted arrays + exp weights
__global__ __launch_bounds__(256) void k_rank(const float* __restrict__ s2,
        int* __restrict__ order, float* __restrict__ s2s,
        double* __restrict__ wpos, double* __restrict__ wneg) {
    __shared__ float sk[NN];      // 32 KB: all of s2
    __shared__ int part[256];
    const int tid = threadIdx.x;
    {
        const float4* src = reinterpret_cast<const float4*>(s2);
        float4* dst = reinterpret_cast<float4*>(sk);
        #pragma unroll
        for (int t = 0; t < 8; ++t) dst[tid + t * 256] = src[tid + t * 256];
    }
    __syncthreads();
    const int jl = tid & 15, seg = tid >> 4;   // 16 j's x 16 segments of 512
    const int j = blockIdx.x * 16 + jl;
    const float mine = sk[j];
    const int base = seg * 512;
    int cnt = 0;
    for (int q = 0; q < 128; ++q) {
        const int e = (q * 4 + seg * 4) & 511;   // rotate start to spread banks
        const int idx = base + e;
        const float4 v = *reinterpret_cast<const float4*>(&sk[idx]);
        cnt += (v.x < mine) | ((v.x == mine) & (idx     < j));
        cnt += (v.y < mine) | ((v.y == mine) & (idx + 1 < j));
        cnt += (v.z < mine) | ((v.z == mine) & (idx + 2 < j));
        cnt += (v.w < mine) | ((v.w == mine) & (idx + 3 < j));
    }
    part[tid] = cnt;
    __syncthreads();
    if (tid < 16) {
        int r = 0;
        #pragma unroll
        for (int s = 0; s < 16; ++s) r += part[s * 16 + tid];
        const float v = mine;   // tid<16 => seg==0, jl==tid
        order[r] = blockIdx.x * 16 + tid;
        s2s[r] = v;
        wpos[r] = exp((double)v);
        wneg[r] = exp(0.2 * (double)v);
    }
}

// ============ K3: h1sT[d][r] = h1[order[r]][d]  (coalesced via LDS transpose)
__global__ __launch_bounds__(256) void k_gather(const float* __restrict__ h1,
        const int* __restrict__ order, float* __restrict__ h1sT) {
    __shared__ float t[64][65];
    const int lane = threadIdx.x & 63, w = threadIdx.x >> 6;
    const int r0 = blockIdx.x * 64;
    for (int i = 0; i < 16; ++i) {
        const int lr = w * 16 + i;
        const int row = order[r0 + lr];
        t[lr][lane] = h1[(size_t)row * DF + lane];
    }
    __syncthreads();
    for (int i = 0; i < 16; ++i) {
        const int dd = w * 16 + i;
        h1sT[(size_t)dd * NN + r0 + lane] = t[lane][dd];
    }
}

// ============ K4: per-(col,chunk) totals
__global__ __launch_bounds__(256) void k_chunksum(const float* __restrict__ h1sT,
        const double* __restrict__ wpos, const double* __restrict__ wneg,
        double* __restrict__ cT) {
    const int col = blockIdx.x >> 5, c = blockIdx.x & 31;
    const int p = c * 256 + threadIdx.x;
    const int d = (col < 65) ? col : col - 65;
    const double wgt = (col < 65) ? wpos[p] : wneg[p];
    double val = (d < DF) ? wgt * (double)h1sT[(size_t)d * NN + p] : wgt;
    #pragma unroll
    for (int off = 32; off; off >>= 1) val += __shfl_xor(val, off);
    __shared__ double red[4];
    const int lane = threadIdx.x & 63, w = threadIdx.x >> 6;
    if (lane == 0) red[w] = val;
    __syncthreads();
    if (threadIdx.x == 0) cT[blockIdx.x] = red[0] + red[1] + red[2] + red[3];
}

// ============ K5: exclusive scan -> E  (chunk offset from cT inlined; c==31 writes totals)
__global__ __launch_bounds__(256) void k_scan(const float* __restrict__ h1sT,
        const double* __restrict__ wpos, const double* __restrict__ wneg,
        const double* __restrict__ cT, double* __restrict__ E) {
    const int col = blockIdx.x >> 5, c = blockIdx.x & 31;
    const int tid = threadIdx.x, lane = tid & 63, w = tid >> 6;
    const int p = c * 256 + tid;
    const int d = (col < 65) ? col : col - 65;
    const double wgt = (col < 65) ? wpos[p] : wneg[p];
    const double val = (d < DF) ? wgt * (double)h1sT[(size_t)d * NN + p] : wgt;
    double cOv = 0.0;                       // prefix over earlier chunks (scalar loads)
    for (int cc = 0; cc < c; ++cc) cOv += cT[(size_t)col * NCH + cc];
    double incl = val;
    #pragma unroll
    for (int off = 1; off < 64; off <<= 1) {
        double tv = __shfl_up(incl, off);
        if (lane >= off) incl += tv;
    }
    __shared__ double wtot[4];
    if (lane == 63) wtot[w] = incl;
    __syncthreads();
    double woff = cOv;
    for (int ww = 0; ww < w; ++ww) woff += wtot[ww];
    E[(size_t)p * NCOL + col] = woff + incl - val;
    if (c == NCH - 1 && tid == 255) E[(size_t)NN * NCOL + col] = woff + incl;
}

// ============ K6: per-row binary search + combine
__global__ __launch_bounds__(256) void k_out(const float* __restrict__ s1,
        const float* __restrict__ s2s, const double* __restrict__ E,
        float* __restrict__ out) {
    const int lane = threadIdx.x & 63, wave = threadIdx.x >> 6;
    const int i = blockIdx.x * 4 + wave;
    const float s1v = s1[i];
    const float t = -s1v;
    int lo = 0, hi = NN;
    while (lo < hi) {
        int mid = (lo + hi) >> 1;
        if (s2s[mid] < t) lo = mid + 1; else hi = mid;
    }
    const double* Ek = E + (size_t)lo * NCOL;
    const double* Et = E + (size_t)NN * NCOL;
    const double e1 = exp((double)s1v);
    const double e2 = exp(0.2 * (double)s1v);
    const double num = e1 * (Et[lane] - Ek[lane]) + e2 * Ek[65 + lane];
    const double den = e1 * (Et[DF] - Ek[DF]) + e2 * Ek[65 + DF];
    out[(size_t)i * DF + lane] = (float)(num / den);
}

extern "C" void kernel_launch(void* const* d_in, const int* in_sizes, int n_in,
                              void* d_out, int out_size, void* d_ws, size_t ws_size,
                              hipStream_t stream) {
    const float* x    = (const float*)d_in[0];
    const float* nmat = (const float*)d_in[1];
    const float* W    = (const float*)d_in[2];
    const float* w1   = (const float*)d_in[3];
    const float* w2   = (const float*)d_in[4];
    float* out = (float*)d_out;

    char* ws = (char*)d_ws;
    size_t off = 0;
    auto alloc = [&](size_t bytes) -> void* {
        void* p = ws + off;
        off += (bytes + 255) & ~(size_t)255;
        return p;
    };
    float*  h1    = (float*)alloc((size_t)NN * DF * 4);       // 2 MB
    float*  h1sT  = (float*)alloc((size_t)DF * NN * 4);       // 2 MB (rank-ordered, transposed)
    float*  s1    = (float*)alloc((size_t)NN * 4);
    float*  s2    = (float*)alloc((size_t)NN * 4);
    int*    order = (int*)alloc((size_t)NN * 4);
    float*  s2s   = (float*)alloc((size_t)NN * 4);
    double* wpos  = (double*)alloc((size_t)NN * 8);
    double* wneg  = (double*)alloc((size_t)NN * 8);
    double* cT    = (double*)alloc((size_t)NCOL * NCH * 8);
    double* E     = (double*)alloc((size_t)(NN + 1) * NCOL * 8); // 8.5 MB

    k_main<<<512, 256, 0, stream>>>(x, nmat, W, w1, w2, h1, s1, s2);
    k_rank<<<512, 256, 0, stream>>>(s2, order, s2s, wpos, wneg);
    k_gather<<<128, 256, 0, stream>>>(h1, order, h1sT);
    k_chunksum<<<NCOL * NCH, 256, 0, stream>>>(h1sT, wpos, wneg, cT);
    k_scan<<<NCOL * NCH, 256, 0, stream>>>(h1sT, wpos, wneg, cT, E);
    k_out<<<NN / 4, 256, 0, stream>>>(s1, s2s, E, out);
}